// Round 4
// baseline (164.834 us; speedup 1.0000x reference)
//
#include <hip/hip_runtime.h>

#define NIN  128
#define NOUT 128
#define NN   256   // N
#define BB   4     // batch

// Native vector type: __builtin_nontemporal_store rejects HIP_vector_type.
typedef float f4 __attribute__((ext_vector_type(4)));

// Fully fused, one launch. Grid = 512 blocks (one per (b,o)), block = 1024
// threads (16 waves) -> 2 blocks/CU x 16 waves = 32 waves/CU = full occupancy.
//
// Phase 1 (no redundancy): 1024 threads = 2 channel-halves x {ui,uj} x 256 j.
//   Each thread: 64 FMAs over its half of the channels; LDS partial + reduce.
// Phase 2: out[b,o,i,j] = adj[b,i,j] * (i==j ? ui[j] : uj[j]).
//   Wave w handles rows 16w..16w+15; each wave-store is a contiguous 1 KiB row.
//   Nontemporal stores: out is write-once, keep adj resident in L2.
__global__ __launch_bounds__(1024, 2) void nodeconv_fused(
    const float* __restrict__ adj,   // [B,1,N,N]
    const float* __restrict__ node,  // [B,NIN,N]
    const float* __restrict__ Wi,    // [NOUT,NIN]
    const float* __restrict__ Wj,    // [NOUT,NIN]
    float* __restrict__ out)         // [B,NOUT,N,N]
{
    __shared__ float part[2][2][NN];   // [half][sel][j]  (4 KiB)
    __shared__ float si[NN];
    __shared__ float sj[NN];

    const int bo = blockIdx.x;
    const int b  = bo >> 7;
    const int o  = bo & (NOUT - 1);
    const int t  = threadIdx.x;

    // ---- Phase 1: u{i,j}[j] = sum_c W{i,j}[o,c] * node[b,c,j] ----
    {
        const int j   = t & 255;
        const int sel = (t >> 8) & 1;    // 0 -> ui, 1 -> uj
        const int h   = t >> 9;          // channel half: 0 or 1
        const float* w   = (sel ? Wj : Wi) + o * NIN + h * 64;   // block-uniform
        const float* np_ = node + ((size_t)b * NIN + h * 64) * NN + j;
        float a = 0.f;
        #pragma unroll 16
        for (int c = 0; c < 64; ++c)
            a = fmaf(w[c], np_[(size_t)c * NN], a);
        part[h][sel][j] = a;
    }
    __syncthreads();
    if (t < 512) {
        const int j   = t & 255;
        const int sel = t >> 8;
        const float v = part[0][sel][j] + part[1][sel][j];
        (sel ? sj : si)[j] = v;
    }
    __syncthreads();

    // ---- Phase 2: stream the 256x256 tile ----
    const int jb = (t & 63) << 2;        // base column (fixed per thread)
    const int rr = t >> 6;               // wave id 0..15 -> row group

    const f4 vj = *(const f4*)&sj[jb];   // hoisted off-diagonal values

    const float* adjb = adj + (size_t)b * (NN * NN);
    float*       outp = out + (size_t)bo * (NN * NN);

    const int ibase = rr << 4;           // rows ibase .. ibase+15
    #pragma unroll 8
    for (int r = 0; r < 16; ++r) {
        const int i = ibase + r;
        const float s_ii = si[i];        // wave-uniform LDS broadcast
        const f4 a = *(const f4*)&adjb[i * NN + jb];
        f4 v;
        v.x = (i == jb + 0) ? s_ii : vj.x;
        v.y = (i == jb + 1) ? s_ii : vj.y;
        v.z = (i == jb + 2) ? s_ii : vj.z;
        v.w = (i == jb + 3) ? s_ii : vj.w;
        f4 rs = a * v;
        __builtin_nontemporal_store(rs, (f4*)&outp[i * NN + jb]);
    }
}

extern "C" void kernel_launch(void* const* d_in, const int* in_sizes, int n_in,
                              void* d_out, int out_size, void* d_ws, size_t ws_size,
                              hipStream_t stream) {
    const float* adj  = (const float*)d_in[0];  // [4,1,256,256]
    const float* node = (const float*)d_in[1];  // [4,128,256]
    const float* Wi   = (const float*)d_in[2];  // [128,128]
    const float* Wj   = (const float*)d_in[3];  // [128,128]
    float* out = (float*)d_out;                 // [4,128,256,256]

    nodeconv_fused<<<dim3(BB * NOUT), dim3(1024), 0, stream>>>(adj, node, Wi, Wj, out);
}

// Round 5
// 152.210 us; speedup vs baseline: 1.0829x; 1.0829x over previous
//
#include <hip/hip_runtime.h>

#define NIN  128
#define NOUT 128
#define NN   256   // N
#define BB   4     // batch

typedef float f4 __attribute__((ext_vector_type(4)));

// ---------------- Kernel A: u{i,j}[b,o,j] = sum_c W{i,j}[o,c] * node[b,c,j] ----------------
// 512 blocks (one per b,o), 256 threads (one per j). Writes 2 x 512 KB to ws.
__global__ __launch_bounds__(256) void precompute_u(
    const float* __restrict__ node,  // [B,NIN,N]
    const float* __restrict__ Wi,    // [NOUT,NIN]
    const float* __restrict__ Wj,    // [NOUT,NIN]
    float* __restrict__ ui,          // [B*NOUT, N]
    float* __restrict__ uj)          // [B*NOUT, N]
{
    const int bo = blockIdx.x;
    const int b  = bo >> 7;
    const int o  = bo & (NOUT - 1);
    const int t  = threadIdx.x;

    const float* np_ = node + (size_t)b * NIN * NN + t;  // coalesced across lanes
    const float* wi  = Wi + o * NIN;                     // block-uniform -> scalar loads
    const float* wj  = Wj + o * NIN;

    float ai = 0.f, aj = 0.f;
    #pragma unroll 16
    for (int c = 0; c < NIN; ++c) {
        const float n = np_[c * NN];
        ai = fmaf(wi[c], n, ai);
        aj = fmaf(wj[c], n, aj);
    }
    ui[bo * NN + t] = ai;
    uj[bo * NN + t] = aj;
}

// ---------------- Kernel B: out[b,o,i,j] = adj[b,i,j] * (i==j ? ui[j] : uj[j]) -------------
// 2048 blocks: (b,o) x 4 row-chunks of 64 rows -> 8 blocks/CU (full 2048-thread
// residency). 256 threads: 64 float4 cols x 4 row-phases; 16 independent
// load->mul->store iterations per thread (long store stream, fill-kernel style).
__global__ __launch_bounds__(256) void stream_out(
    const float* __restrict__ adj,   // [B,1,N,N]
    const float* __restrict__ ui,    // [B*NOUT, N]
    const float* __restrict__ uj,    // [B*NOUT, N]
    float* __restrict__ out)         // [B,NOUT,N,N]
{
    const int blk = blockIdx.x;
    const int bo  = blk >> 2;
    const int qc  = blk & 3;          // 64-row chunk
    const int b   = bo >> 7;
    const int t   = threadIdx.x;
    const int jb  = (t & 63) << 2;    // base column (fixed per thread)
    const int rr  = t >> 6;           // 0..3

    const f4 vj = *(const f4*)&uj[bo * NN + jb];   // hoisted off-diagonal values
    const float* uip  = ui + bo * NN;
    const float* adjb = adj + (size_t)b * (NN * NN);
    float*       outp = out + (size_t)bo * (NN * NN);

    const int i0 = (qc << 6) + rr;    // rows i0, i0+4, ..., i0+60
    #pragma unroll
    for (int r = 0; r < 16; ++r) {
        const int i = i0 + (r << 2);
        const float s_ii = uip[i];                     // same addr across wave -> broadcast
        const f4 a = *(const f4*)&adjb[i * NN + jb];
        f4 v;
        v.x = (i == jb + 0) ? s_ii : vj.x;
        v.y = (i == jb + 1) ? s_ii : vj.y;
        v.z = (i == jb + 2) ? s_ii : vj.z;
        v.w = (i == jb + 3) ? s_ii : vj.w;
        *(f4*)&outp[i * NN + jb] = a * v;              // 1 KiB contiguous per wave
    }
}

// ---------------- Fallback (ws too small): round-1 fused kernel --------------------------
__global__ __launch_bounds__(256) void nodeconv_fused(
    const float* __restrict__ adj, const float* __restrict__ node,
    const float* __restrict__ Wi, const float* __restrict__ Wj,
    float* __restrict__ out)
{
    __shared__ float si[NN];
    __shared__ float sj[NN];
    const int bo = blockIdx.x;
    const int b  = bo >> 7;
    const int o  = bo & (NOUT - 1);
    const int t  = threadIdx.x;
    {
        const float* np_ = node + (size_t)(b * NIN) * NN + t;
        const float* wi  = Wi + o * NIN;
        const float* wj  = Wj + o * NIN;
        float ai = 0.f, aj = 0.f;
        #pragma unroll 8
        for (int c = 0; c < NIN; ++c) {
            const float n = np_[(size_t)c * NN];
            ai += wi[c] * n;
            aj += wj[c] * n;
        }
        si[t] = ai;
        sj[t] = aj;
    }
    __syncthreads();
    const int jb   = (t & 63) << 2;
    const int rrow = t >> 6;
    const f4 vj = *(const f4*)&sj[jb];
    const float* adjb = adj + (size_t)b * (NN * NN);
    float*       outp = out + (size_t)bo * (NN * NN);
    #pragma unroll 4
    for (int r = 0; r < 64; ++r) {
        const int i = (r << 2) + rrow;
        const float s_ii = si[i];
        const f4 a = *(const f4*)&adjb[i * NN + jb];
        f4 v;
        v.x = (i == jb + 0) ? s_ii : vj.x;
        v.y = (i == jb + 1) ? s_ii : vj.y;
        v.z = (i == jb + 2) ? s_ii : vj.z;
        v.w = (i == jb + 3) ? s_ii : vj.w;
        *(f4*)&outp[i * NN + jb] = a * v;
    }
}

extern "C" void kernel_launch(void* const* d_in, const int* in_sizes, int n_in,
                              void* d_out, int out_size, void* d_ws, size_t ws_size,
                              hipStream_t stream) {
    const float* adj  = (const float*)d_in[0];  // [4,1,256,256]
    const float* node = (const float*)d_in[1];  // [4,128,256]
    const float* Wi   = (const float*)d_in[2];  // [128,128]
    const float* Wj   = (const float*)d_in[3];  // [128,128]
    float* out = (float*)d_out;                 // [4,128,256,256]

    const size_t u_elems = (size_t)BB * NOUT * NN;          // 131072
    const size_t need    = 2 * u_elems * sizeof(float);     // 1 MiB

    if (ws_size >= need) {
        float* ui = (float*)d_ws;
        float* uj = ui + u_elems;
        precompute_u<<<dim3(BB * NOUT), dim3(256), 0, stream>>>(node, Wi, Wj, ui, uj);
        stream_out<<<dim3(BB * NOUT * 4), dim3(256), 0, stream>>>(adj, ui, uj, out);
    } else {
        nodeconv_fused<<<dim3(BB * NOUT), dim3(256), 0, stream>>>(adj, node, Wi, Wj, out);
    }
}